// Round 7
// baseline (298.596 us; speedup 1.0000x reference)
//
#include <hip/hip_runtime.h>
#include <cmath>

#define NN 8192
#define DD 512
#define NSRC 8
#define PSW 8                  // ps partials per row = 8 column groups
#define COFF 100.0f            // fixed softmax offset

typedef __bf16 bf16x8 __attribute__((ext_vector_type(8)));
typedef float  f32x4  __attribute__((ext_vector_type(4)));

__device__ __forceinline__ unsigned short f2bf(float f) {
    unsigned u = __float_as_uint(f);
    u += 0x7fffu + ((u >> 16) & 1u);
    return (unsigned short)(u >> 16);
}

// ---------------------------------------------------------------------------
// Kernel A: blocks 0..127 per-source text sums; blocks 128+ cast fp32->bf16.
// ---------------------------------------------------------------------------
__global__ __launch_bounds__(256) void k_prep(
    const float* __restrict__ img, const float* __restrict__ txt,
    const int* __restrict__ labels,
    unsigned short* __restrict__ imgB, unsigned short* __restrict__ txtB,
    float* __restrict__ Tsum, int* __restrict__ counts)
{
    const int tid = threadIdx.x;
    if (blockIdx.x >= 128) {
        const size_t gid = (size_t)(blockIdx.x - 128) * 256 + tid;
        const size_t half = (size_t)NN * DD / 8;
        const float* src = (gid < half) ? img : txt;
        unsigned short* dst = (gid < half) ? imgB : txtB;
        const size_t off = ((gid < half) ? gid : gid - half) * 8;
        const float4 v0 = *(const float4*)(src + off);
        const float4 v1 = *(const float4*)(src + off + 4);
        union { unsigned short s[8]; uint4 v; } o;
        o.s[0] = f2bf(v0.x); o.s[1] = f2bf(v0.y); o.s[2] = f2bf(v0.z); o.s[3] = f2bf(v0.w);
        o.s[4] = f2bf(v1.x); o.s[5] = f2bf(v1.y); o.s[6] = f2bf(v1.z); o.s[7] = f2bf(v1.w);
        *(uint4*)(dst + off) = o.v;
        return;
    }
    __shared__ float Tacc[NSRC * DD];
    __shared__ int cacc[NSRC];
    const int d0 = 2 * tid;
#pragma unroll
    for (int s = 0; s < NSRC; s++) {
        Tacc[s * DD + d0] = 0.f;
        Tacc[s * DD + d0 + 1] = 0.f;
    }
    if (tid < NSRC) cacc[tid] = 0;
    __syncthreads();

    const int row0 = blockIdx.x * 64;
    if (tid < 64) atomicAdd(&cacc[labels[row0 + tid]], 1);

    for (int j = 0; j < 64; j++) {
        const int lab = labels[row0 + j];
        const float2 v = *(const float2*)(txt + (size_t)(row0 + j) * DD + d0);
        Tacc[lab * DD + d0]     += v.x;
        Tacc[lab * DD + d0 + 1] += v.y;
    }
    __syncthreads();
#pragma unroll
    for (int k = 0; k < NSRC * DD / 256; k++) {
        const int e = k * 256 + tid;
        atomicAdd(&Tsum[e], Tacc[e]);
    }
    if (tid < NSRC) atomicAdd(&counts[tid], cacc[tid]);
}

// ---------------------------------------------------------------------------
// Kernel B (R7): 16x16 MFMA (R4's proven 0-conflict read pattern) with a TRUE
// cross-phase software pipeline:
//  - both bf sets held live (bf0,bf1): 24 reads/wave/tile (was 32, -25% LDS)
//  - every phase issues the NEXT phase's fragment reads before its MFMA
//    cluster (balance 4/8/8/4); consumption is one phase later across a
//    barrier -> LDS drains read(p+1) while MFMA runs phase p.
//  - counted waits relocated to gate cross-tile reads:
//      ph3: vmcnt(6)  [outstanding 8 -> drains A(t+1)q0q2, exactly what
//                      af' (ih0: wr0->q0, wr1->q2) reads from NXT]
//      ph4: vmcnt(2)  [drains ph1's 6 -> tile t+1 complete -> bf0' safe]
//  - 1 barrier/phase (4/tile, was 8). Every LDS WAR chain has >=1 barrier
//    between read-completion (pre-consuming-MFMA, pre-end-barrier) and the
//    overwriting STG (verified per region).
//  - sched_barrier(0) pins the read/stage block above each MFMA cluster.
// ---------------------------------------------------------------------------
__global__ __launch_bounds__(512, 2) void k_lse_mfma256(
    const unsigned short* __restrict__ imgB, const unsigned short* __restrict__ txtB,
    const float* __restrict__ scale_p, float* __restrict__ ps)
{
    __shared__ uint4 lds[8192];            // 128 KiB
    const float scale = scale_p[0];
    const int tid  = threadIdx.x;
    const int lane = tid & 63;
    const int w    = tid >> 6;
    const int wr   = w >> 2;
    const int wc   = w & 3;
    const int lq   = lane >> 4;
    const int ln   = lane & 15;
    const int c    = blockIdx.x & 7;       // XCD (round-robin dispatch)
    const int l    = blockIdx.x >> 3;
    const int by   = c * 4 + (l >> 3);     // row panel 0..31
    const int bcg  = l & 7;                // column group 0..7
    const int row0    = by * 256;
    const int colBase = bcg * 1024;

    const int st_r  = tid >> 3;
    const int st_kc = (tid & 7) ^ (st_r & 7);
    const int xsw   = ln & 7;

    int rowA[2][4], colB[2][2];
#pragma unroll
    for (int ih = 0; ih < 2; ih++)
#pragma unroll
        for (int ii = 0; ii < 4; ii++)
            rowA[ih][ii] = (wr * 128 + ih * 64 + ii * 16 + ln) * 8;
#pragma unroll
    for (int jh = 0; jh < 2; jh++)
#pragma unroll
        for (int jj = 0; jj < 2; jj++)
            colB[jh][jj] = (wc * 64 + jh * 32 + jj * 16 + ln) * 8;

#define SA(BUF, Q, T)                                                          \
    { const unsigned short* g = imgB + (size_t)(row0 + (Q) * 64 + st_r) * DD   \
          + (((T) & 7) << 6) + (st_kc << 3);                                   \
      __builtin_amdgcn_global_load_lds(                                        \
          (const __attribute__((address_space(1))) void*)g,                    \
          (__attribute__((address_space(3))) void*)                            \
              &lds[(BUF) * 4096 + (Q) * 512 + tid], 16, 0, 0); }
#define SB(BUF, Q, T)                                                          \
    { const unsigned short* g = txtB                                           \
          + (size_t)(colBase + ((((T) >> 3) & 3) << 8) + (Q) * 64 + st_r) * DD \
          + (((T) & 7) << 6) + (st_kc << 3);                                   \
      __builtin_amdgcn_global_load_lds(                                        \
          (const __attribute__((address_space(1))) void*)g,                    \
          (__attribute__((address_space(3))) void*)                            \
              &lds[(BUF) * 4096 + 2048 + (Q) * 512 + tid], 16, 0, 0); }

#define RD_AF(DST, BUF, IH)                                                    \
    _Pragma("unroll") for (int ks = 0; ks < 2; ks++)                           \
        _Pragma("unroll") for (int ii = 0; ii < 4; ii++)                       \
            DST[ii][ks] = *reinterpret_cast<const bf16x8*>(                    \
                &lds[(BUF) * 4096 + rowA[IH][ii] + (((ks << 2) + lq) ^ xsw)]);

#define RD_BF(DST, BUF, JH)                                                    \
    _Pragma("unroll") for (int ks = 0; ks < 2; ks++)                           \
        _Pragma("unroll") for (int jj = 0; jj < 2; jj++)                       \
            DST[jj][ks] = *reinterpret_cast<const bf16x8*>(                    \
                &lds[(BUF) * 4096 + 2048 + colB[JH][jj] + (((ks << 2) + lq) ^ xsw)]);

#define MM(AF, IB, BF, JB)                                                     \
    _Pragma("unroll") for (int ks = 0; ks < 2; ks++)                           \
        _Pragma("unroll") for (int ii = 0; ii < 4; ii++)                       \
            _Pragma("unroll") for (int jj = 0; jj < 2; jj++)                   \
                acc[(IB) + ii][(JB) + jj] =                                    \
                    __builtin_amdgcn_mfma_f32_16x16x32_bf16(                   \
                        AF[ii][ks], BF[jj][ks], acc[(IB) + ii][(JB) + jj],     \
                        0, 0, 0);

// One K-tile in BUF; NXT = BUF^1. Entry state: afA = BUF ih0 (loaded prev
// ph3), bf0 = BUF jh0 (loaded prev ph4). Exit state: afA/bf0 hold NXT's.
#define TILE_(BUF, NXT, STG1, STG3)                                            \
    do {                                                                       \
        /* ph1 (ih0,jh0): prefetch bf1; stage 6 of tile t+1 -> NXT */          \
        RD_BF(bf1, BUF, 1);                                                    \
        STG1;                                                                  \
        __builtin_amdgcn_sched_barrier(0);                                     \
        __builtin_amdgcn_s_setprio(1);                                         \
        MM(afA, 0, bf0, 0);                                                    \
        __builtin_amdgcn_s_setprio(0);                                         \
        __builtin_amdgcn_s_barrier();                                          \
        /* ph2 (ih0,jh1): prefetch afB */                                      \
        RD_AF(afB, BUF, 1);                                                    \
        __builtin_amdgcn_sched_barrier(0);                                     \
        __builtin_amdgcn_s_setprio(1);                                         \
        MM(afA, 0, bf1, 2);                                                    \
        __builtin_amdgcn_s_setprio(0);                                         \
        __builtin_amdgcn_s_barrier();                                          \
        /* ph3 (ih1,jh0): vmcnt(6) gates next-tile afA; stage 2 -> BUF */      \
        asm volatile("s_waitcnt vmcnt(6)" ::: "memory");                       \
        RD_AF(afA, NXT, 0);                                                    \
        STG3;                                                                  \
        __builtin_amdgcn_sched_barrier(0);                                     \
        __builtin_amdgcn_s_setprio(1);                                         \
        MM(afB, 4, bf0, 0);                                                    \
        __builtin_amdgcn_s_setprio(0);                                         \
        __builtin_amdgcn_s_barrier();                                          \
        /* ph4 (ih1,jh1): vmcnt(2) gates next-tile bf0 */                      \
        asm volatile("s_waitcnt vmcnt(2)" ::: "memory");                       \
        RD_BF(bf0, NXT, 0);                                                    \
        __builtin_amdgcn_sched_barrier(0);                                     \
        __builtin_amdgcn_s_setprio(1);                                         \
        MM(afB, 4, bf1, 2);                                                    \
        __builtin_amdgcn_s_setprio(0);                                         \
        __builtin_amdgcn_s_barrier();                                          \
    } while (0)

    // ---- prologue: tile 0 fully + tile 1 Aq0,Aq2; preload afA/bf0 ----
#pragma unroll
    for (int q = 0; q < 4; q++) SA(0, q, 0);
#pragma unroll
    for (int q = 0; q < 4; q++) SB(0, q, 0);
    SA(1, 0, 1); SA(1, 2, 1);
    asm volatile("s_waitcnt vmcnt(2)" ::: "memory");   // tile 0 landed
    __builtin_amdgcn_s_barrier();

    f32x4 acc[8][4];
    f32x4 s_run[8];
#pragma unroll
    for (int i = 0; i < 8; i++) {
        s_run[i] = (f32x4){0.f, 0.f, 0.f, 0.f};
#pragma unroll
        for (int j = 0; j < 4; j++) acc[i][j] = (f32x4){0.f, 0.f, 0.f, 0.f};
    }
    bf16x8 afA[4][2], afB[4][2], bf0[2][2], bf1[2][2];
    RD_AF(afA, 0, 0);
    RD_BF(bf0, 0, 0);

#pragma unroll 1
    for (int v0 = 0; v0 < 32; v0 += 2) {
        TILE_(0, 1,
              SA(1, 1, v0 + 1); SA(1, 3, v0 + 1);
              SB(1, 0, v0 + 1); SB(1, 1, v0 + 1);
              SB(1, 2, v0 + 1); SB(1, 3, v0 + 1),
              SA(0, 0, v0 + 2); SA(0, 2, v0 + 2));
        TILE_(1, 0,
              SA(0, 1, v0 + 2); SA(0, 3, v0 + 2);
              SB(0, 0, v0 + 2); SB(0, 1, v0 + 2);
              SB(0, 2, v0 + 2); SB(0, 3, v0 + 2),
              SA(1, 0, v0 + 3); SA(1, 2, v0 + 3));
        if ((v0 & 6) == 6) {
            // ct boundary: register-only exp flush (no barrier, no loads)
#pragma unroll
            for (int i = 0; i < 8; i++) {
#pragma unroll
                for (int rg = 0; rg < 4; rg++) {
                    float es = s_run[i][rg];
#pragma unroll
                    for (int j = 0; j < 4; j++)
                        es += __expf(fmaf(acc[i][j][rg], scale, -COFF));
                    s_run[i][rg] = es;
                }
#pragma unroll
                for (int j = 0; j < 4; j++)
                    acc[i][j] = (f32x4){0.f, 0.f, 0.f, 0.f};
            }
        }
    }

    asm volatile("s_waitcnt vmcnt(0)" ::: "memory");
    __syncthreads();

    // ---- epilogue: reduce s_run across ln, fold 4 wc-waves via LDS ----
    float* fred = (float*)lds;
#pragma unroll
    for (int i = 0; i < 8; i++) {
#pragma unroll
        for (int rg = 0; rg < 4; rg++) {
            float es = s_run[i][rg];
#pragma unroll
            for (int off = 8; off; off >>= 1) es += __shfl_xor(es, off);
            if (ln == 0)
                fred[(wr * 128 + i * 16 + lq * 4 + rg) * 4 + wc] = es;
        }
    }
    __syncthreads();
    if (tid < 256) {
        const float tot = fred[tid * 4] + fred[tid * 4 + 1]
                        + fred[tid * 4 + 2] + fred[tid * 4 + 3];
        ps[(size_t)(row0 + tid) * PSW + bcg] = tot;
    }
#undef SA
#undef SB
#undef RD_AF
#undef RD_BF
#undef MM
#undef TILE_
}

// ---------------------------------------------------------------------------
// Kernel C: combine partials -> lse, per-row fp32 dot products, reduce.
// ---------------------------------------------------------------------------
__global__ __launch_bounds__(256) void k_finalize(
    const float* __restrict__ img, const float* __restrict__ txt,
    const int* __restrict__ labels, const float* __restrict__ scale_p,
    const float* __restrict__ Tsum, const int* __restrict__ counts,
    const float* __restrict__ ps,
    float* __restrict__ out)
{
    const float scale = scale_p[0];
    const int tid = threadIdx.x;
    const int lane = tid & 63;
    const int wave = tid >> 6;
    const int rowBase = blockIdx.x * 16 + wave * 4;
    float local = 0.f;
#pragma unroll
    for (int it = 0; it < 4; it++) {
        const int i = rowBase + it;
        const int lab = labels[i];
        float ds = 0.f, dt = 0.f;
        const float* ip = img + (size_t)i * DD;
        const float* tp = txt + (size_t)i * DD;
        const float* sp = Tsum + lab * DD;
#pragma unroll
        for (int k = lane; k < DD; k += 64) {
            const float a = ip[k];
            ds = fmaf(a, tp[k], ds);
            dt = fmaf(a, sp[k], dt);
        }
        float es = (lane < PSW) ? ps[(size_t)i * PSW + lane] : 0.f;
#pragma unroll
        for (int off = 32; off; off >>= 1) {
            ds += __shfl_xor(ds, off);
            dt += __shfl_xor(dt, off);
            es += __shfl_xor(es, off);
        }
        if (lane == 0) {
            const float lse = COFF + __logf(es);
            const int cnt = counts[lab] - 1;
            if (cnt > 0) {
                const float row_sum = scale * (dt - ds) - (float)cnt * lse;
                local += row_sum / (float)cnt;
            }
        }
    }
    __shared__ float red[4];
    if (lane == 0) red[wave] = local;
    __syncthreads();
    if (tid == 0) {
        const float t = red[0] + red[1] + red[2] + red[3];
        atomicAdd(out, -t / (float)NN);
    }
}

// ---------------------------------------------------------------------------
extern "C" void kernel_launch(void* const* d_in, const int* in_sizes, int n_in,
                              void* d_out, int out_size, void* d_ws, size_t ws_size,
                              hipStream_t stream)
{
    const float* img     = (const float*)d_in[0];
    const float* txt     = (const float*)d_in[1];
    const float* scale_p = (const float*)d_in[2];
    const int*   labels  = (const int*)d_in[3];
    float* out = (float*)d_out;

    char* ws = (char*)d_ws;
    float* ps    = (float*)(ws);                                  // 256 KB (8192 x 8)
    float* Tsum  = (float*)(ws + (1 << 18));                      // 16 KB
    int*   counts = (int*)(ws + (1 << 18) + NSRC * DD * 4);
    unsigned short* imgB = (unsigned short*)(ws + 2 * 1024 * 1024);   // 8 MB
    unsigned short* txtB = (unsigned short*)(ws + 10 * 1024 * 1024);  // 8 MB

    hipMemsetAsync(ws + (1 << 18), 0, NSRC * DD * 4 + 64, stream);  // Tsum+counts
    hipMemsetAsync(d_out, 0, 4, stream);                            // out

    k_prep<<<128 + (2 * NN * DD / 8) / 256, 256, 0, stream>>>(
        img, txt, labels, imgB, txtB, Tsum, counts);
    k_lse_mfma256<<<256, 512, 0, stream>>>(imgB, txtB, scale_p, ps);
    k_finalize<<<NN / 16, 256, 0, stream>>>(img, txt, labels, scale_p,
                                            Tsum, counts, ps, out);
}

// Round 8
// 207.848 us; speedup vs baseline: 1.4366x; 1.4366x over previous
//
#include <hip/hip_runtime.h>
#include <cmath>

#define NN 8192
#define DD 512
#define NSRC 8
#define PSW 8                  // ps partials per row = 8 column groups
#define COFF 100.0f            // fixed softmax offset

typedef __bf16 bf16x8 __attribute__((ext_vector_type(8)));
typedef float  f32x4  __attribute__((ext_vector_type(4)));

__device__ __forceinline__ unsigned short f2bf(float f) {
    unsigned u = __float_as_uint(f);
    u += 0x7fffu + ((u >> 16) & 1u);
    return (unsigned short)(u >> 16);
}

// ---------------------------------------------------------------------------
// Kernel A: blocks 0..127 per-source text sums; blocks 128+ cast fp32->bf16.
// ---------------------------------------------------------------------------
__global__ __launch_bounds__(256) void k_prep(
    const float* __restrict__ img, const float* __restrict__ txt,
    const int* __restrict__ labels,
    unsigned short* __restrict__ imgB, unsigned short* __restrict__ txtB,
    float* __restrict__ Tsum, int* __restrict__ counts)
{
    const int tid = threadIdx.x;
    if (blockIdx.x >= 128) {
        const size_t gid = (size_t)(blockIdx.x - 128) * 256 + tid;
        const size_t half = (size_t)NN * DD / 8;
        const float* src = (gid < half) ? img : txt;
        unsigned short* dst = (gid < half) ? imgB : txtB;
        const size_t off = ((gid < half) ? gid : gid - half) * 8;
        const float4 v0 = *(const float4*)(src + off);
        const float4 v1 = *(const float4*)(src + off + 4);
        union { unsigned short s[8]; uint4 v; } o;
        o.s[0] = f2bf(v0.x); o.s[1] = f2bf(v0.y); o.s[2] = f2bf(v0.z); o.s[3] = f2bf(v0.w);
        o.s[4] = f2bf(v1.x); o.s[5] = f2bf(v1.y); o.s[6] = f2bf(v1.z); o.s[7] = f2bf(v1.w);
        *(uint4*)(dst + off) = o.v;
        return;
    }
    __shared__ float Tacc[NSRC * DD];
    __shared__ int cacc[NSRC];
    const int d0 = 2 * tid;
#pragma unroll
    for (int s = 0; s < NSRC; s++) {
        Tacc[s * DD + d0] = 0.f;
        Tacc[s * DD + d0 + 1] = 0.f;
    }
    if (tid < NSRC) cacc[tid] = 0;
    __syncthreads();

    const int row0 = blockIdx.x * 64;
    if (tid < 64) atomicAdd(&cacc[labels[row0 + tid]], 1);

    for (int j = 0; j < 64; j++) {
        const int lab = labels[row0 + j];
        const float2 v = *(const float2*)(txt + (size_t)(row0 + j) * DD + d0);
        Tacc[lab * DD + d0]     += v.x;
        Tacc[lab * DD + d0 + 1] += v.y;
    }
    __syncthreads();
#pragma unroll
    for (int k = 0; k < NSRC * DD / 256; k++) {
        const int e = k * 256 + tid;
        atomicAdd(&Tsum[e], Tacc[e]);
    }
    if (tid < NSRC) atomicAdd(&counts[tid], cacc[tid]);
}

// ---------------------------------------------------------------------------
// Kernel B (R8): R4's staging/vmcnt machinery, restructured to ONE barrier
// pair per K-tile so the LDS and MFMA pipes overlap (R4/R5 measured phase =
// serial LDS 753 + MFMA 620 cyc; the per-phase barriers enforced that).
//  - reads 24/wave/tile (B read once: bf0,bf1 held; was 32)
//  - tile body: {af0,bf0,bf1 reads + STG1} -> sched_barrier -> MFMA1 ->
//    {af1 reads} -> MFMA2 -> bar_A -> STG4 -> MFMA3,MFMA4 -> vmcnt(2) -> bar_B
//    Compiler emits fine-grained lgkmcnt (m97 evidence), so MFMA1 starts
//    after 12 reads while the rest drain underneath the MFMA clusters.
//  - register budget FIXED FIRST (R7 post-mortem: spill at 200MB scratch):
//    s_run (32 VGPR) eliminated -- ct-flush shuffle-reduces immediately and
//    accumulates into sacc[256][4] LDS (4KB, one writer lane per cell).
//    Peak frag liveness ~40 < R4's 56. WRITE_SIZE is the spill detector.
//  - safety: vmcnt invariant unchanged (enter tile: 2 outstanding; +6+2;
//    vmcnt(2) drains exactly tile t+1 before bar_B). STG4 overwrites BUF
//    q0/q2 whose only readers (af0) completed before bar_A. STG1 targets
//    NXT, last read before previous bar_B. af1 (q1/q3) disjoint from STG4.
// ---------------------------------------------------------------------------
__global__ __launch_bounds__(512, 2) void k_lse_mfma256(
    const unsigned short* __restrict__ imgB, const unsigned short* __restrict__ txtB,
    const float* __restrict__ scale_p, float* __restrict__ ps)
{
    __shared__ uint4 lds[8192];            // 128 KiB tile buffers
    __shared__ float sacc[1024];           // 4 KiB expsum accumulator [row][wc]
    const float scale = scale_p[0];
    const int tid  = threadIdx.x;
    const int lane = tid & 63;
    const int w    = tid >> 6;
    const int wr   = w >> 2;
    const int wc   = w & 3;
    const int lq   = lane >> 4;
    const int ln   = lane & 15;
    const int c    = blockIdx.x & 7;       // XCD (round-robin dispatch)
    const int l    = blockIdx.x >> 3;
    const int by   = c * 4 + (l >> 3);     // row panel 0..31
    const int bcg  = l & 7;                // column group 0..7
    const int row0    = by * 256;
    const int colBase = bcg * 1024;

    const int st_r  = tid >> 3;
    const int st_kc = (tid & 7) ^ (st_r & 7);
    const int xsw   = ln & 7;

    int rowA[2][4], colB[2][2];
#pragma unroll
    for (int ih = 0; ih < 2; ih++)
#pragma unroll
        for (int ii = 0; ii < 4; ii++)
            rowA[ih][ii] = (wr * 128 + ih * 64 + ii * 16 + ln) * 8;
#pragma unroll
    for (int jh = 0; jh < 2; jh++)
#pragma unroll
        for (int jj = 0; jj < 2; jj++)
            colB[jh][jj] = (wc * 64 + jh * 32 + jj * 16 + ln) * 8;

#define SA(BUF, Q, T)                                                          \
    { const unsigned short* g = imgB + (size_t)(row0 + (Q) * 64 + st_r) * DD   \
          + (((T) & 7) << 6) + (st_kc << 3);                                   \
      __builtin_amdgcn_global_load_lds(                                        \
          (const __attribute__((address_space(1))) void*)g,                    \
          (__attribute__((address_space(3))) void*)                            \
              &lds[(BUF) * 4096 + (Q) * 512 + tid], 16, 0, 0); }
#define SB(BUF, Q, T)                                                          \
    { const unsigned short* g = txtB                                           \
          + (size_t)(colBase + ((((T) >> 3) & 3) << 8) + (Q) * 64 + st_r) * DD \
          + (((T) & 7) << 6) + (st_kc << 3);                                   \
      __builtin_amdgcn_global_load_lds(                                        \
          (const __attribute__((address_space(1))) void*)g,                    \
          (__attribute__((address_space(3))) void*)                            \
              &lds[(BUF) * 4096 + 2048 + (Q) * 512 + tid], 16, 0, 0); }

#define RD_AF(DST, BUF, IH)                                                    \
    _Pragma("unroll") for (int ks = 0; ks < 2; ks++)                           \
        _Pragma("unroll") for (int ii = 0; ii < 4; ii++)                       \
            DST[ii][ks] = *reinterpret_cast<const bf16x8*>(                    \
                &lds[(BUF) * 4096 + rowA[IH][ii] + (((ks << 2) + lq) ^ xsw)]);

#define RD_BF(DST, BUF, JH)                                                    \
    _Pragma("unroll") for (int ks = 0; ks < 2; ks++)                           \
        _Pragma("unroll") for (int jj = 0; jj < 2; jj++)                       \
            DST[jj][ks] = *reinterpret_cast<const bf16x8*>(                    \
                &lds[(BUF) * 4096 + 2048 + colB[JH][jj] + (((ks << 2) + lq) ^ xsw)]);

#define MM(AF, IB, BF, JB)                                                     \
    _Pragma("unroll") for (int ks = 0; ks < 2; ks++)                           \
        _Pragma("unroll") for (int ii = 0; ii < 4; ii++)                       \
            _Pragma("unroll") for (int jj = 0; jj < 2; jj++)                   \
                acc[(IB) + ii][(JB) + jj] =                                    \
                    __builtin_amdgcn_mfma_f32_16x16x32_bf16(                   \
                        AF[ii][ks], BF[jj][ks], acc[(IB) + ii][(JB) + jj],     \
                        0, 0, 0);

// One K-tile resident in BUF. 2 barriers total.
#define TILE_(BUF, STG1, STG4)                                                 \
    do {                                                                       \
        bf16x8 af0[4][2], af1[4][2], bf0[2][2], bf1[2][2];                     \
        RD_AF(af0, BUF, 0);                                                    \
        RD_BF(bf0, BUF, 0);                                                    \
        RD_BF(bf1, BUF, 1);                                                    \
        STG1;                                                                  \
        __builtin_amdgcn_sched_barrier(0);                                     \
        __builtin_amdgcn_s_setprio(1);                                         \
        MM(af0, 0, bf0, 0);                                                    \
        __builtin_amdgcn_s_setprio(0);                                         \
        RD_AF(af1, BUF, 1);                                                    \
        __builtin_amdgcn_sched_barrier(0);                                     \
        __builtin_amdgcn_s_setprio(1);                                         \
        MM(af0, 0, bf1, 2);                                                    \
        __builtin_amdgcn_s_setprio(0);                                         \
        __builtin_amdgcn_s_barrier();   /* bar_A: af0 consumed block-wide */   \
        STG4;                                                                  \
        __builtin_amdgcn_s_setprio(1);                                         \
        MM(af1, 4, bf0, 0);                                                    \
        MM(af1, 4, bf1, 2);                                                    \
        __builtin_amdgcn_s_setprio(0);                                         \
        asm volatile("s_waitcnt vmcnt(2)" ::: "memory");                       \
        __builtin_amdgcn_s_barrier();   /* bar_B: tile t+1 staged */           \
    } while (0)

    // ---- prologue: zero sacc; stage tile 0 fully + tile 1 Aq0,Aq2 ----
    sacc[tid] = 0.f;
    sacc[tid + 512] = 0.f;
#pragma unroll
    for (int q = 0; q < 4; q++) SA(0, q, 0);
#pragma unroll
    for (int q = 0; q < 4; q++) SB(0, q, 0);
    SA(1, 0, 1); SA(1, 2, 1);
    asm volatile("s_waitcnt vmcnt(2)" ::: "memory");   // tile 0 landed
    __builtin_amdgcn_s_barrier();                      // also orders sacc init

    f32x4 acc[8][4];
#pragma unroll
    for (int i = 0; i < 8; i++)
#pragma unroll
        for (int j = 0; j < 4; j++) acc[i][j] = (f32x4){0.f, 0.f, 0.f, 0.f};

#pragma unroll 1
    for (int v0 = 0; v0 < 32; v0 += 2) {
        TILE_(0,
              SA(1, 1, v0 + 1); SA(1, 3, v0 + 1);
              SB(1, 0, v0 + 1); SB(1, 1, v0 + 1);
              SB(1, 2, v0 + 1); SB(1, 3, v0 + 1),
              SA(0, 0, v0 + 2); SA(0, 2, v0 + 2));
        TILE_(1,
              SA(0, 1, v0 + 2); SA(0, 3, v0 + 2);
              SB(0, 0, v0 + 2); SB(0, 1, v0 + 2);
              SB(0, 2, v0 + 2); SB(0, 3, v0 + 2),
              SA(1, 0, v0 + 3); SA(1, 2, v0 + 3));
        if ((v0 & 6) == 6) {
            // ct boundary: exp + ln-shuffle-reduce + accumulate into sacc.
            // One writer lane per (row,wc) cell -> race-free; region never
            // touched by staging; next read is the final epilogue.
#pragma unroll
            for (int i = 0; i < 8; i++) {
#pragma unroll
                for (int rg = 0; rg < 4; rg++) {
                    float es = __expf(fmaf(acc[i][0][rg], scale, -COFF))
                             + __expf(fmaf(acc[i][1][rg], scale, -COFF))
                             + __expf(fmaf(acc[i][2][rg], scale, -COFF))
                             + __expf(fmaf(acc[i][3][rg], scale, -COFF));
#pragma unroll
                    for (int off = 8; off; off >>= 1) es += __shfl_xor(es, off);
                    if (ln == 0)
                        sacc[(wr * 128 + i * 16 + lq * 4 + rg) * 4 + wc] += es;
                }
#pragma unroll
                for (int j = 0; j < 4; j++)
                    acc[i][j] = (f32x4){0.f, 0.f, 0.f, 0.f};
            }
        }
    }

    asm volatile("s_waitcnt vmcnt(0)" ::: "memory");
    __syncthreads();

    // ---- epilogue: fold 4 wc partials per row, write ps ----
    if (tid < 256) {
        const float tot = sacc[tid * 4] + sacc[tid * 4 + 1]
                        + sacc[tid * 4 + 2] + sacc[tid * 4 + 3];
        ps[(size_t)(row0 + tid) * PSW + bcg] = tot;
    }
#undef SA
#undef SB
#undef RD_AF
#undef RD_BF
#undef MM
#undef TILE_
}

// ---------------------------------------------------------------------------
// Kernel C: combine partials -> lse, per-row fp32 dot products, reduce.
// ---------------------------------------------------------------------------
__global__ __launch_bounds__(256) void k_finalize(
    const float* __restrict__ img, const float* __restrict__ txt,
    const int* __restrict__ labels, const float* __restrict__ scale_p,
    const float* __restrict__ Tsum, const int* __restrict__ counts,
    const float* __restrict__ ps,
    float* __restrict__ out)
{
    const float scale = scale_p[0];
    const int tid = threadIdx.x;
    const int lane = tid & 63;
    const int wave = tid >> 6;
    const int rowBase = blockIdx.x * 16 + wave * 4;
    float local = 0.f;
#pragma unroll
    for (int it = 0; it < 4; it++) {
        const int i = rowBase + it;
        const int lab = labels[i];
        float ds = 0.f, dt = 0.f;
        const float* ip = img + (size_t)i * DD;
        const float* tp = txt + (size_t)i * DD;
        const float* sp = Tsum + lab * DD;
#pragma unroll
        for (int k = lane; k < DD; k += 64) {
            const float a = ip[k];
            ds = fmaf(a, tp[k], ds);
            dt = fmaf(a, sp[k], dt);
        }
        float es = (lane < PSW) ? ps[(size_t)i * PSW + lane] : 0.f;
#pragma unroll
        for (int off = 32; off; off >>= 1) {
            ds += __shfl_xor(ds, off);
            dt += __shfl_xor(dt, off);
            es += __shfl_xor(es, off);
        }
        if (lane == 0) {
            const float lse = COFF + __logf(es);
            const int cnt = counts[lab] - 1;
            if (cnt > 0) {
                const float row_sum = scale * (dt - ds) - (float)cnt * lse;
                local += row_sum / (float)cnt;
            }
        }
    }
    __shared__ float red[4];
    if (lane == 0) red[wave] = local;
    __syncthreads();
    if (tid == 0) {
        const float t = red[0] + red[1] + red[2] + red[3];
        atomicAdd(out, -t / (float)NN);
    }
}

// ---------------------------------------------------------------------------
extern "C" void kernel_launch(void* const* d_in, const int* in_sizes, int n_in,
                              void* d_out, int out_size, void* d_ws, size_t ws_size,
                              hipStream_t stream)
{
    const float* img     = (const float*)d_in[0];
    const float* txt     = (const float*)d_in[1];
    const float* scale_p = (const float*)d_in[2];
    const int*   labels  = (const int*)d_in[3];
    float* out = (float*)d_out;

    char* ws = (char*)d_ws;
    float* ps    = (float*)(ws);                                  // 256 KB (8192 x 8)
    float* Tsum  = (float*)(ws + (1 << 18));                      // 16 KB
    int*   counts = (int*)(ws + (1 << 18) + NSRC * DD * 4);
    unsigned short* imgB = (unsigned short*)(ws + 2 * 1024 * 1024);   // 8 MB
    unsigned short* txtB = (unsigned short*)(ws + 10 * 1024 * 1024);  // 8 MB

    hipMemsetAsync(ws + (1 << 18), 0, NSRC * DD * 4 + 64, stream);  // Tsum+counts
    hipMemsetAsync(d_out, 0, 4, stream);                            // out

    k_prep<<<128 + (2 * NN * DD / 8) / 256, 256, 0, stream>>>(
        img, txt, labels, imgB, txtB, Tsum, counts);
    k_lse_mfma256<<<256, 512, 0, stream>>>(imgB, txtB, scale_p, ps);
    k_finalize<<<NN / 16, 256, 0, stream>>>(img, txt, labels, scale_p,
                                            Tsum, counts, ps, out);
}

// Round 9
// 165.469 us; speedup vs baseline: 1.8046x; 1.2561x over previous
//
#include <hip/hip_runtime.h>
#include <cmath>

#define NN 8192
#define DD 512
#define NSRC 8
#define PSW 8                  // ps partials per row = 8 column groups
#define COFF 100.0f            // fixed softmax offset

typedef __bf16 bf16x8 __attribute__((ext_vector_type(8)));
typedef float  f32x4  __attribute__((ext_vector_type(4)));

__device__ __forceinline__ unsigned short f2bf(float f) {
    unsigned u = __float_as_uint(f);
    u += 0x7fffu + ((u >> 16) & 1u);
    return (unsigned short)(u >> 16);
}

// ---------------------------------------------------------------------------
// Kernel A: blocks 0..127 per-source text sums; blocks 128+ cast fp32->bf16.
// ---------------------------------------------------------------------------
__global__ __launch_bounds__(256) void k_prep(
    const float* __restrict__ img, const float* __restrict__ txt,
    const int* __restrict__ labels,
    unsigned short* __restrict__ imgB, unsigned short* __restrict__ txtB,
    float* __restrict__ Tsum, int* __restrict__ counts)
{
    const int tid = threadIdx.x;
    if (blockIdx.x >= 128) {
        const size_t gid = (size_t)(blockIdx.x - 128) * 256 + tid;
        const size_t half = (size_t)NN * DD / 8;
        const float* src = (gid < half) ? img : txt;
        unsigned short* dst = (gid < half) ? imgB : txtB;
        const size_t off = ((gid < half) ? gid : gid - half) * 8;
        const float4 v0 = *(const float4*)(src + off);
        const float4 v1 = *(const float4*)(src + off + 4);
        union { unsigned short s[8]; uint4 v; } o;
        o.s[0] = f2bf(v0.x); o.s[1] = f2bf(v0.y); o.s[2] = f2bf(v0.z); o.s[3] = f2bf(v0.w);
        o.s[4] = f2bf(v1.x); o.s[5] = f2bf(v1.y); o.s[6] = f2bf(v1.z); o.s[7] = f2bf(v1.w);
        *(uint4*)(dst + off) = o.v;
        return;
    }
    __shared__ float Tacc[NSRC * DD];
    __shared__ int cacc[NSRC];
    const int d0 = 2 * tid;
#pragma unroll
    for (int s = 0; s < NSRC; s++) {
        Tacc[s * DD + d0] = 0.f;
        Tacc[s * DD + d0 + 1] = 0.f;
    }
    if (tid < NSRC) cacc[tid] = 0;
    __syncthreads();

    const int row0 = blockIdx.x * 64;
    if (tid < 64) atomicAdd(&cacc[labels[row0 + tid]], 1);

    for (int j = 0; j < 64; j++) {
        const int lab = labels[row0 + j];
        const float2 v = *(const float2*)(txt + (size_t)(row0 + j) * DD + d0);
        Tacc[lab * DD + d0]     += v.x;
        Tacc[lab * DD + d0 + 1] += v.y;
    }
    __syncthreads();
#pragma unroll
    for (int k = 0; k < NSRC * DD / 256; k++) {
        const int e = k * 256 + tid;
        atomicAdd(&Tsum[e], Tacc[e]);
    }
    if (tid < NSRC) atomicAdd(&counts[tid], cacc[tid]);
}

// ---------------------------------------------------------------------------
// Kernel B (R9): R4's phase machine BYTE-IDENTICAL in sync structure
// (8 phases / 2 K-tiles, barrier + lgkmcnt(0) pin + sched_barrier + setprio,
// STG at ph1/ph3/ph5/ph7, vmcnt(2) at ph4/ph8, same prologue) — but the wave
// grid is 4wr x 2wc with SINGLE-READ fragments:
//   per wave 64 rows x 128 cols; af[4] read once per tile (ph JH0, held 4
//   phases), each bf[jh] read once. LDS traffic/K-tile/CU: A 32KB x2 +
//   B 32KB x4 = 192 KB (R4: 256 KB, -25%) -> drain 578 avg cyc/phase.
//   Every ds_read keeps R4's exact 16-row/ln/lq/xsw pattern (0 conflicts;
//   R6's conflicts came from 32-row fragments, not the grid).
// WAR: af reads complete in ph1 (pin) >=2 barriers before ph3/ph5 overwrite;
// bf[JH] read in phase JH, last ph4, overwritten ph5. vmcnt algebra as R4.
// ---------------------------------------------------------------------------
__global__ __launch_bounds__(512, 2) void k_lse_mfma256(
    const unsigned short* __restrict__ imgB, const unsigned short* __restrict__ txtB,
    const float* __restrict__ scale_p, float* __restrict__ ps)
{
    __shared__ uint4 lds[8192];            // 128 KiB
    const float scale = scale_p[0];
    const int tid  = threadIdx.x;
    const int lane = tid & 63;
    const int w    = tid >> 6;
    const int wr   = w >> 1;               // 0..3: 64-row quarter
    const int wc   = w & 1;                // 0..1: 128-col half
    const int lq   = lane >> 4;
    const int ln   = lane & 15;
    const int c    = blockIdx.x & 7;       // XCD (round-robin dispatch)
    const int l    = blockIdx.x >> 3;
    const int by   = c * 4 + (l >> 3);     // row panel 0..31
    const int bcg  = l & 7;                // column group 0..7
    const int row0    = by * 256;
    const int colBase = bcg * 1024;

    const int st_r  = tid >> 3;
    const int st_kc = (tid & 7) ^ (st_r & 7);
    const int xsw   = ln & 7;

    int rowA[4], colB[4][2];
#pragma unroll
    for (int ii = 0; ii < 4; ii++)
        rowA[ii] = (wr * 64 + ii * 16 + ln) * 8;
#pragma unroll
    for (int jh = 0; jh < 4; jh++)
#pragma unroll
        for (int jj = 0; jj < 2; jj++)
            colB[jh][jj] = (wc * 128 + jh * 32 + jj * 16 + ln) * 8;

#define SA(BUF, Q, T)                                                          \
    { const unsigned short* g = imgB + (size_t)(row0 + (Q) * 64 + st_r) * DD   \
          + (((T) & 7) << 6) + (st_kc << 3);                                   \
      __builtin_amdgcn_global_load_lds(                                        \
          (const __attribute__((address_space(1))) void*)g,                    \
          (__attribute__((address_space(3))) void*)                            \
              &lds[(BUF) * 4096 + (Q) * 512 + tid], 16, 0, 0); }
#define SB(BUF, Q, T)                                                          \
    { const unsigned short* g = txtB                                           \
          + (size_t)(colBase + ((((T) >> 3) & 3) << 8) + (Q) * 64 + st_r) * DD \
          + (((T) & 7) << 6) + (st_kc << 3);                                   \
      __builtin_amdgcn_global_load_lds(                                        \
          (const __attribute__((address_space(1))) void*)g,                    \
          (__attribute__((address_space(3))) void*)                            \
              &lds[(BUF) * 4096 + 2048 + (Q) * 512 + tid], 16, 0, 0); }

// Phase JH of a tile in BUF. RA=1 only at JH0 (af read once, held all tile).
#define PHASE_(BUF, JH, RA, STG, VM)                                           \
    do {                                                                       \
        if (RA) {                                                              \
            _Pragma("unroll") for (int ks = 0; ks < 2; ks++)                   \
                _Pragma("unroll") for (int ii = 0; ii < 4; ii++)               \
                    af[ii][ks] = *reinterpret_cast<const bf16x8*>(             \
                        &lds[(BUF) * 4096 + rowA[ii]                           \
                             + (((ks << 2) + lq) ^ xsw)]);                     \
        }                                                                      \
        bf16x8 bf[2][2];                                                       \
        _Pragma("unroll") for (int ks = 0; ks < 2; ks++)                       \
            _Pragma("unroll") for (int jj = 0; jj < 2; jj++)                   \
                bf[jj][ks] = *reinterpret_cast<const bf16x8*>(                 \
                    &lds[(BUF) * 4096 + 2048 + colB[JH][jj]                    \
                         + (((ks << 2) + lq) ^ xsw)]);                         \
        STG;                                                                   \
        __builtin_amdgcn_s_barrier();                                          \
        asm volatile("s_waitcnt lgkmcnt(0)" ::: "memory");                     \
        __builtin_amdgcn_sched_barrier(0);                                     \
        __builtin_amdgcn_s_setprio(1);                                         \
        _Pragma("unroll") for (int ks = 0; ks < 2; ks++) {                     \
            _Pragma("unroll") for (int ii = 0; ii < 4; ii++) {                 \
                _Pragma("unroll") for (int jj = 0; jj < 2; jj++) {             \
                    acc[ii][(JH) * 2 + jj] =                                   \
                        __builtin_amdgcn_mfma_f32_16x16x32_bf16(               \
                            af[ii][ks], bf[jj][ks], acc[ii][(JH) * 2 + jj],    \
                            0, 0, 0);                                          \
                }                                                              \
            }                                                                  \
        }                                                                      \
        __builtin_amdgcn_s_setprio(0);                                         \
        if (VM) { asm volatile("s_waitcnt vmcnt(2)" ::: "memory"); }           \
        __builtin_amdgcn_s_barrier();                                          \
    } while (0)

    // ---- prologue: tile 0 fully + tile 1 Aq0,Aq2 (as R4) ----
#pragma unroll
    for (int q = 0; q < 4; q++) SA(0, q, 0);
#pragma unroll
    for (int q = 0; q < 4; q++) SB(0, q, 0);
    SA(1, 0, 1); SA(1, 2, 1);
    asm volatile("s_waitcnt vmcnt(2)" ::: "memory");   // tile 0 landed
    __builtin_amdgcn_s_barrier();

    f32x4 acc[4][8];
    f32x4 s_run[4];
#pragma unroll
    for (int i = 0; i < 4; i++) {
        s_run[i] = (f32x4){0.f, 0.f, 0.f, 0.f};
#pragma unroll
        for (int j = 0; j < 8; j++) acc[i][j] = (f32x4){0.f, 0.f, 0.f, 0.f};
    }
    bf16x8 af[4][2];

#pragma unroll 1
    for (int v0 = 0; v0 < 32; v0 += 2) {
        PHASE_(0, 0, 1,
               SA(1, 1, v0 + 1); SA(1, 3, v0 + 1);
               SB(1, 0, v0 + 1); SB(1, 1, v0 + 1);
               SB(1, 2, v0 + 1); SB(1, 3, v0 + 1), 0);
        PHASE_(0, 1, 0, (void)0, 0);
        PHASE_(0, 2, 0, SA(0, 0, v0 + 2); SA(0, 2, v0 + 2), 0);
        PHASE_(0, 3, 0, (void)0, 1);
        PHASE_(1, 0, 1,
               SA(0, 1, v0 + 2); SA(0, 3, v0 + 2);
               SB(0, 0, v0 + 2); SB(0, 1, v0 + 2);
               SB(0, 2, v0 + 2); SB(0, 3, v0 + 2), 0);
        PHASE_(1, 1, 0, (void)0, 0);
        PHASE_(1, 2, 0, SA(1, 0, v0 + 3); SA(1, 2, v0 + 3), 0);
        PHASE_(1, 3, 0, (void)0, 1);
        if ((v0 & 6) == 6) {
            // ct boundary: register-only exp flush (no barrier, no loads)
#pragma unroll
            for (int i = 0; i < 4; i++) {
#pragma unroll
                for (int rg = 0; rg < 4; rg++) {
                    float es = s_run[i][rg];
#pragma unroll
                    for (int j = 0; j < 8; j++)
                        es += __expf(fmaf(acc[i][j][rg], scale, -COFF));
                    s_run[i][rg] = es;
                }
#pragma unroll
                for (int j = 0; j < 8; j++)
                    acc[i][j] = (f32x4){0.f, 0.f, 0.f, 0.f};
            }
        }
    }

    asm volatile("s_waitcnt vmcnt(0)" ::: "memory");
    __syncthreads();

    // ---- epilogue: reduce s_run across ln, fold 2 wc-waves via LDS ----
    float* fred = (float*)lds;             // 256 rows x 2 wc floats
#pragma unroll
    for (int i = 0; i < 4; i++) {
#pragma unroll
        for (int rg = 0; rg < 4; rg++) {
            float es = s_run[i][rg];
#pragma unroll
            for (int off = 8; off; off >>= 1) es += __shfl_xor(es, off);
            if (ln == 0)
                fred[(wr * 64 + i * 16 + lq * 4 + rg) * 2 + wc] = es;
        }
    }
    __syncthreads();
    if (tid < 256) {
        const float tot = fred[tid * 2] + fred[tid * 2 + 1];
        ps[(size_t)(row0 + tid) * PSW + bcg] = tot;
    }
#undef SA
#undef SB
#undef PHASE_
}

// ---------------------------------------------------------------------------
// Kernel C: combine partials -> lse, per-row fp32 dot products, reduce.
// ---------------------------------------------------------------------------
__global__ __launch_bounds__(256) void k_finalize(
    const float* __restrict__ img, const float* __restrict__ txt,
    const int* __restrict__ labels, const float* __restrict__ scale_p,
    const float* __restrict__ Tsum, const int* __restrict__ counts,
    const float* __restrict__ ps,
    float* __restrict__ out)
{
    const float scale = scale_p[0];
    const int tid = threadIdx.x;
    const int lane = tid & 63;
    const int wave = tid >> 6;
    const int rowBase = blockIdx.x * 16 + wave * 4;
    float local = 0.f;
#pragma unroll
    for (int it = 0; it < 4; it++) {
        const int i = rowBase + it;
        const int lab = labels[i];
        float ds = 0.f, dt = 0.f;
        const float* ip = img + (size_t)i * DD;
        const float* tp = txt + (size_t)i * DD;
        const float* sp = Tsum + lab * DD;
#pragma unroll
        for (int k = lane; k < DD; k += 64) {
            const float a = ip[k];
            ds = fmaf(a, tp[k], ds);
            dt = fmaf(a, sp[k], dt);
        }
        float es = (lane < PSW) ? ps[(size_t)i * PSW + lane] : 0.f;
#pragma unroll
        for (int off = 32; off; off >>= 1) {
            ds += __shfl_xor(ds, off);
            dt += __shfl_xor(dt, off);
            es += __shfl_xor(es, off);
        }
        if (lane == 0) {
            const float lse = COFF + __logf(es);
            const int cnt = counts[lab] - 1;
            if (cnt > 0) {
                const float row_sum = scale * (dt - ds) - (float)cnt * lse;
                local += row_sum / (float)cnt;
            }
        }
    }
    __shared__ float red[4];
    if (lane == 0) red[wave] = local;
    __syncthreads();
    if (tid == 0) {
        const float t = red[0] + red[1] + red[2] + red[3];
        atomicAdd(out, -t / (float)NN);
    }
}

// ---------------------------------------------------------------------------
extern "C" void kernel_launch(void* const* d_in, const int* in_sizes, int n_in,
                              void* d_out, int out_size, void* d_ws, size_t ws_size,
                              hipStream_t stream)
{
    const float* img     = (const float*)d_in[0];
    const float* txt     = (const float*)d_in[1];
    const float* scale_p = (const float*)d_in[2];
    const int*   labels  = (const int*)d_in[3];
    float* out = (float*)d_out;

    char* ws = (char*)d_ws;
    float* ps    = (float*)(ws);                                  // 256 KB (8192 x 8)
    float* Tsum  = (float*)(ws + (1 << 18));                      // 16 KB
    int*   counts = (int*)(ws + (1 << 18) + NSRC * DD * 4);
    unsigned short* imgB = (unsigned short*)(ws + 2 * 1024 * 1024);   // 8 MB
    unsigned short* txtB = (unsigned short*)(ws + 10 * 1024 * 1024);  // 8 MB

    hipMemsetAsync(ws + (1 << 18), 0, NSRC * DD * 4 + 64, stream);  // Tsum+counts
    hipMemsetAsync(d_out, 0, 4, stream);                            // out

    k_prep<<<128 + (2 * NN * DD / 8) / 256, 256, 0, stream>>>(
        img, txt, labels, imgB, txtB, Tsum, counts);
    k_lse_mfma256<<<256, 512, 0, stream>>>(imgB, txtB, scale_p, ps);
    k_finalize<<<NN / 16, 256, 0, stream>>>(img, txt, labels, scale_p,
                                            Tsum, counts, ps, out);
}

// Round 10
// 158.571 us; speedup vs baseline: 1.8830x; 1.0435x over previous
//
#include <hip/hip_runtime.h>
#include <cmath>

#define NN 8192
#define DD 512
#define NSRC 8
#define PSW 8                  // ps partials per row = 8 column groups
#define COFF 100.0f            // fixed softmax offset

typedef __bf16 bf16x8 __attribute__((ext_vector_type(8)));
typedef float  f32x4  __attribute__((ext_vector_type(4)));

__device__ __forceinline__ unsigned short f2bf(float f) {
    unsigned u = __float_as_uint(f);
    u += 0x7fffu + ((u >> 16) & 1u);
    return (unsigned short)(u >> 16);
}

// ---------------------------------------------------------------------------
// Kernel A (R10): blocks 0..127 per-source text sums (unchanged); blocks
// 128.. : wave-per-row cast of img+txt AND per-row img.txt dot (ds) computed
// for free while both fp32 rows are in registers (removes k_finalize's 64 MB
// fp32 re-read).
// ---------------------------------------------------------------------------
__global__ __launch_bounds__(256) void k_prep(
    const float* __restrict__ img, const float* __restrict__ txt,
    const int* __restrict__ labels,
    unsigned short* __restrict__ imgB, unsigned short* __restrict__ txtB,
    float* __restrict__ Tsum, int* __restrict__ counts,
    float* __restrict__ dsv)
{
    const int tid = threadIdx.x;
    if (blockIdx.x >= 128) {
        const int wv   = tid >> 6;
        const int lane = tid & 63;
        const int row  = (blockIdx.x - 128) * 4 + wv;
        const size_t base = (size_t)row * DD + lane * 8;
        const float4 i0 = *(const float4*)(img + base);
        const float4 i1 = *(const float4*)(img + base + 4);
        const float4 t0 = *(const float4*)(txt + base);
        const float4 t1 = *(const float4*)(txt + base + 4);
        union { unsigned short s[8]; uint4 v; } oi, ot;
        oi.s[0] = f2bf(i0.x); oi.s[1] = f2bf(i0.y); oi.s[2] = f2bf(i0.z); oi.s[3] = f2bf(i0.w);
        oi.s[4] = f2bf(i1.x); oi.s[5] = f2bf(i1.y); oi.s[6] = f2bf(i1.z); oi.s[7] = f2bf(i1.w);
        ot.s[0] = f2bf(t0.x); ot.s[1] = f2bf(t0.y); ot.s[2] = f2bf(t0.z); ot.s[3] = f2bf(t0.w);
        ot.s[4] = f2bf(t1.x); ot.s[5] = f2bf(t1.y); ot.s[6] = f2bf(t1.z); ot.s[7] = f2bf(t1.w);
        *(uint4*)(imgB + base) = oi.v;
        *(uint4*)(txtB + base) = ot.v;
        float ds = i0.x * t0.x + i0.y * t0.y + i0.z * t0.z + i0.w * t0.w
                 + i1.x * t1.x + i1.y * t1.y + i1.z * t1.z + i1.w * t1.w;
#pragma unroll
        for (int off = 32; off; off >>= 1) ds += __shfl_xor(ds, off);
        if (lane == 0) dsv[row] = ds;
        return;
    }
    __shared__ float Tacc[NSRC * DD];
    __shared__ int cacc[NSRC];
    const int d0 = 2 * tid;
#pragma unroll
    for (int s = 0; s < NSRC; s++) {
        Tacc[s * DD + d0] = 0.f;
        Tacc[s * DD + d0 + 1] = 0.f;
    }
    if (tid < NSRC) cacc[tid] = 0;
    __syncthreads();

    const int row0 = blockIdx.x * 64;
    if (tid < 64) atomicAdd(&cacc[labels[row0 + tid]], 1);

    for (int j = 0; j < 64; j++) {
        const int lab = labels[row0 + j];
        const float2 v = *(const float2*)(txt + (size_t)(row0 + j) * DD + d0);
        Tacc[lab * DD + d0]     += v.x;
        Tacc[lab * DD + d0 + 1] += v.y;
    }
    __syncthreads();
#pragma unroll
    for (int k = 0; k < NSRC * DD / 256; k++) {
        const int e = k * 256 + tid;
        atomicAdd(&Tsum[e], Tacc[e]);
    }
    if (tid < NSRC) atomicAdd(&counts[tid], cacc[tid]);
}

// ---------------------------------------------------------------------------
// Kernel B (R10): R9's machine with (a) 4 JH-phases merged to 2 HALF-phases
// (same reads/MFMA/stage placement/vmcnt algebra, half the barriers: 8->4 per
// tile) and (b) all ds_read addresses collapsed to 8 precomputed byte-offset
// base registers (aA/aB per buf x ks; ii/jh/jj deltas are compile-time and
// fold into the ds_read offset field) + 2 precomputed global staging base
// pointers (kills the address rematerialization behind VALUBusy=30%).
// Stage schedule per 2 tiles (R4-proven): PH(0,0): 6 loads t+1->buf1;
// PH(0,1): 2 loads A(t+2)q0q2->buf0 + vmcnt(2); PH(1,0): 6 loads t+2->buf0;
// PH(1,1): 2 loads A(t+3)q0q2->buf1 + vmcnt(2). Outstanding at each wait =
// 2+6+2=10 -> drains exactly one whole tile. WAR: every overwritten region's
// readers completed before the preceding end-barrier (af/bf reads complete
// pre-MFMA via the lgkm pin; STGs are >=1 barrier downstream).
// ---------------------------------------------------------------------------
__global__ __launch_bounds__(512, 2) void k_lse_mfma256(
    const unsigned short* __restrict__ imgB, const unsigned short* __restrict__ txtB,
    const float* __restrict__ scale_p, float* __restrict__ ps)
{
    __shared__ uint4 lds[8192];            // 128 KiB
    const float scale = scale_p[0];
    const int tid  = threadIdx.x;
    const int lane = tid & 63;
    const int w    = tid >> 6;
    const int wr   = w >> 1;               // 0..3: 64-row quarter
    const int wc   = w & 1;                // 0..1: 128-col half
    const int lq   = lane >> 4;
    const int ln   = lane & 15;
    const int c    = blockIdx.x & 7;       // XCD (round-robin dispatch)
    const int l    = blockIdx.x >> 3;
    const int by   = c * 4 + (l >> 3);     // row panel 0..31
    const int bcg  = l & 7;                // column group 0..7
    const int row0    = by * 256;
    const int colBase = bcg * 1024;

    const int st_r  = tid >> 3;
    const int st_kc = (tid & 7) ^ (st_r & 7);
    const int xsw   = ln & 7;

    // precomputed ds_read base byte-offsets: [buf][ks]; ii/jh/jj deltas are
    // compile-time constants folded into the ds_read offset immediate.
    int aA[2][2], aB[2][2];
#pragma unroll
    for (int b = 0; b < 2; b++)
#pragma unroll
        for (int ks = 0; ks < 2; ks++) {
            const int perm = ((ks << 2) + lq) ^ xsw;
            aA[b][ks] = b * 65536 + ((wr * 64 + ln) * 8 + perm) * 16;
            aB[b][ks] = b * 65536 + 32768 + ((wc * 128 + ln) * 8 + perm) * 16;
        }
    // precomputed global staging bases (element units)
    const unsigned short* gA0 = imgB + (size_t)(row0 + st_r) * DD + (st_kc << 3);
    const unsigned short* gB0 = txtB + (size_t)(colBase + st_r) * DD + (st_kc << 3);

#define SA(BUF, Q, T)                                                          \
    { const unsigned short* g = gA0 + ((Q) << 15) + (((T) & 7) << 6);          \
      __builtin_amdgcn_global_load_lds(                                        \
          (const __attribute__((address_space(1))) void*)g,                    \
          (__attribute__((address_space(3))) void*)                            \
              &lds[(BUF) * 4096 + (Q) * 512 + tid], 16, 0, 0); }
#define SB(BUF, Q, T)                                                          \
    { const unsigned short* g = gB0 + ((size_t)(((T) >> 3) & 3) << 17)         \
          + ((Q) << 15) + (((T) & 7) << 6);                                    \
      __builtin_amdgcn_global_load_lds(                                        \
          (const __attribute__((address_space(1))) void*)g,                    \
          (__attribute__((address_space(3))) void*)                            \
              &lds[(BUF) * 4096 + 2048 + (Q) * 512 + tid], 16, 0, 0); }

// HALF 0: read af (8) + bf jh0,1 (8), MFMA JH0+JH1 (32).
// HALF 1: read bf jh2,3 (8), MFMA JH2+JH3 (32). af held across both halves.
#define PH_(BUF, HALF, STG, VM)                                                \
    do {                                                                       \
        if (!(HALF)) {                                                         \
            _Pragma("unroll") for (int ks = 0; ks < 2; ks++)                   \
                _Pragma("unroll") for (int ii = 0; ii < 4; ii++)               \
                    af[ii][ks] = *reinterpret_cast<const bf16x8*>(             \
                        (const char*)lds + aA[BUF][ks] + ii * 2048);           \
        }                                                                      \
        bf16x8 bf[2][2][2];                                                    \
        _Pragma("unroll") for (int ks = 0; ks < 2; ks++)                       \
            _Pragma("unroll") for (int j2 = 0; j2 < 2; j2++)                   \
                _Pragma("unroll") for (int jj = 0; jj < 2; jj++)               \
                    bf[j2][jj][ks] = *reinterpret_cast<const bf16x8*>(         \
                        (const char*)lds + aB[BUF][ks]                         \
                        + ((HALF) * 2 + j2) * 4096 + jj * 2048);               \
        STG;                                                                   \
        __builtin_amdgcn_s_barrier();                                          \
        asm volatile("s_waitcnt lgkmcnt(0)" ::: "memory");                     \
        __builtin_amdgcn_sched_barrier(0);                                     \
        __builtin_amdgcn_s_setprio(1);                                         \
        _Pragma("unroll") for (int ks = 0; ks < 2; ks++) {                     \
            _Pragma("unroll") for (int ii = 0; ii < 4; ii++) {                 \
                _Pragma("unroll") for (int j2 = 0; j2 < 2; j2++) {             \
                    _Pragma("unroll") for (int jj = 0; jj < 2; jj++) {         \
                        acc[ii][((HALF) * 2 + j2) * 2 + jj] =                  \
                            __builtin_amdgcn_mfma_f32_16x16x32_bf16(           \
                                af[ii][ks], bf[j2][jj][ks],                    \
                                acc[ii][((HALF) * 2 + j2) * 2 + jj], 0, 0, 0); \
                    }                                                          \
                }                                                              \
            }                                                                  \
        }                                                                      \
        __builtin_amdgcn_s_setprio(0);                                         \
        if (VM) { asm volatile("s_waitcnt vmcnt(2)" ::: "memory"); }           \
        __builtin_amdgcn_s_barrier();                                          \
    } while (0)

    // ---- prologue: tile 0 fully + tile 1 Aq0,Aq2 (as R4/R9) ----
#pragma unroll
    for (int q = 0; q < 4; q++) SA(0, q, 0);
#pragma unroll
    for (int q = 0; q < 4; q++) SB(0, q, 0);
    SA(1, 0, 1); SA(1, 2, 1);
    asm volatile("s_waitcnt vmcnt(2)" ::: "memory");   // tile 0 landed
    __builtin_amdgcn_s_barrier();

    f32x4 acc[4][8];
    f32x4 s_run[4];
#pragma unroll
    for (int i = 0; i < 4; i++) {
        s_run[i] = (f32x4){0.f, 0.f, 0.f, 0.f};
#pragma unroll
        for (int j = 0; j < 8; j++) acc[i][j] = (f32x4){0.f, 0.f, 0.f, 0.f};
    }
    bf16x8 af[4][2];

#pragma unroll 1
    for (int v0 = 0; v0 < 32; v0 += 2) {
        PH_(0, 0,
            SA(1, 1, v0 + 1); SA(1, 3, v0 + 1);
            SB(1, 0, v0 + 1); SB(1, 1, v0 + 1);
            SB(1, 2, v0 + 1); SB(1, 3, v0 + 1), 0);
        PH_(0, 1, SA(0, 0, v0 + 2); SA(0, 2, v0 + 2), 1);
        PH_(1, 0,
            SA(0, 1, v0 + 2); SA(0, 3, v0 + 2);
            SB(0, 0, v0 + 2); SB(0, 1, v0 + 2);
            SB(0, 2, v0 + 2); SB(0, 3, v0 + 2), 0);
        PH_(1, 1, SA(1, 0, v0 + 3); SA(1, 2, v0 + 3), 1);
        if ((v0 & 6) == 6) {
            // ct boundary: register-only exp flush (no barrier, no loads)
#pragma unroll
            for (int i = 0; i < 4; i++) {
#pragma unroll
                for (int rg = 0; rg < 4; rg++) {
                    float es = s_run[i][rg];
#pragma unroll
                    for (int j = 0; j < 8; j++)
                        es += __expf(fmaf(acc[i][j][rg], scale, -COFF));
                    s_run[i][rg] = es;
                }
#pragma unroll
                for (int j = 0; j < 8; j++)
                    acc[i][j] = (f32x4){0.f, 0.f, 0.f, 0.f};
            }
        }
    }

    asm volatile("s_waitcnt vmcnt(0)" ::: "memory");
    __syncthreads();

    // ---- epilogue: reduce s_run across ln, fold 2 wc-waves via LDS ----
    float* fred = (float*)lds;             // 256 rows x 2 wc floats
#pragma unroll
    for (int i = 0; i < 4; i++) {
#pragma unroll
        for (int rg = 0; rg < 4; rg++) {
            float es = s_run[i][rg];
#pragma unroll
            for (int off = 8; off; off >>= 1) es += __shfl_xor(es, off);
            if (ln == 0)
                fred[(wr * 64 + i * 16 + lq * 4 + rg) * 2 + wc] = es;
        }
    }
    __syncthreads();
    if (tid < 256) {
        const float tot = fred[tid * 2] + fred[tid * 2 + 1];
        ps[(size_t)(row0 + tid) * PSW + bcg] = tot;
    }
#undef SA
#undef SB
#undef PH_
}

// ---------------------------------------------------------------------------
// Kernel C (R10): dt via bf16 imgB . fp32 Tsum (16 MB instead of 64 MB fp32);
// ds precomputed by k_prep.
// ---------------------------------------------------------------------------
__global__ __launch_bounds__(256) void k_finalize(
    const unsigned short* __restrict__ imgB,
    const int* __restrict__ labels, const float* __restrict__ scale_p,
    const float* __restrict__ Tsum, const int* __restrict__ counts,
    const float* __restrict__ ps, const float* __restrict__ dsv,
    float* __restrict__ out)
{
    const float scale = scale_p[0];
    const int tid = threadIdx.x;
    const int lane = tid & 63;
    const int wave = tid >> 6;
    const int rowBase = blockIdx.x * 16 + wave * 4;
    float local = 0.f;
#pragma unroll
    for (int it = 0; it < 4; it++) {
        const int i = rowBase + it;
        const int lab = labels[i];
        const float* sp = Tsum + lab * DD + lane * 8;
        union { uint4 v; unsigned short s[8]; } iv;
        iv.v = *(const uint4*)(imgB + (size_t)i * DD + lane * 8);
        const float4 s0 = *(const float4*)(sp);
        const float4 s1 = *(const float4*)(sp + 4);
        float dt = 0.f;
        dt = fmaf(__uint_as_float((unsigned)iv.s[0] << 16), s0.x, dt);
        dt = fmaf(__uint_as_float((unsigned)iv.s[1] << 16), s0.y, dt);
        dt = fmaf(__uint_as_float((unsigned)iv.s[2] << 16), s0.z, dt);
        dt = fmaf(__uint_as_float((unsigned)iv.s[3] << 16), s0.w, dt);
        dt = fmaf(__uint_as_float((unsigned)iv.s[4] << 16), s1.x, dt);
        dt = fmaf(__uint_as_float((unsigned)iv.s[5] << 16), s1.y, dt);
        dt = fmaf(__uint_as_float((unsigned)iv.s[6] << 16), s1.z, dt);
        dt = fmaf(__uint_as_float((unsigned)iv.s[7] << 16), s1.w, dt);
        float es = (lane < PSW) ? ps[(size_t)i * PSW + lane] : 0.f;
#pragma unroll
        for (int off = 32; off; off >>= 1) {
            dt += __shfl_xor(dt, off);
            es += __shfl_xor(es, off);
        }
        if (lane == 0) {
            const float lse = COFF + __logf(es);
            const int cnt = counts[lab] - 1;
            if (cnt > 0) {
                const float row_sum = scale * (dt - dsv[i]) - (float)cnt * lse;
                local += row_sum / (float)cnt;
            }
        }
    }
    __shared__ float red[4];
    if (lane == 0) red[wave] = local;
    __syncthreads();
    if (tid == 0) {
        const float t = red[0] + red[1] + red[2] + red[3];
        atomicAdd(out, -t / (float)NN);
    }
}

// ---------------------------------------------------------------------------
extern "C" void kernel_launch(void* const* d_in, const int* in_sizes, int n_in,
                              void* d_out, int out_size, void* d_ws, size_t ws_size,
                              hipStream_t stream)
{
    const float* img     = (const float*)d_in[0];
    const float* txt     = (const float*)d_in[1];
    const float* scale_p = (const float*)d_in[2];
    const int*   labels  = (const int*)d_in[3];
    float* out = (float*)d_out;

    char* ws = (char*)d_ws;
    float* ps    = (float*)(ws);                                  // 256 KB (8192 x 8)
    float* Tsum  = (float*)(ws + (1 << 18));                      // 16 KB
    int*   counts = (int*)(ws + (1 << 18) + NSRC * DD * 4);
    float* dsv   = (float*)(ws + 0x48000);                        // 32 KB
    unsigned short* imgB = (unsigned short*)(ws + 2 * 1024 * 1024);   // 8 MB
    unsigned short* txtB = (unsigned short*)(ws + 10 * 1024 * 1024);  // 8 MB

    hipMemsetAsync(ws + (1 << 18), 0, NSRC * DD * 4 + 64, stream);  // Tsum+counts
    hipMemsetAsync(d_out, 0, 4, stream);                            // out

    k_prep<<<128 + NN / 4, 256, 0, stream>>>(
        img, txt, labels, imgB, txtB, Tsum, counts, dsv);
    k_lse_mfma256<<<256, 512, 0, stream>>>(imgB, txtB, scale_p, ps);
    k_finalize<<<NN / 16, 256, 0, stream>>>(imgB, labels, scale_p,
                                            Tsum, counts, ps, dsv, out);
}

// Round 11
// 157.377 us; speedup vs baseline: 1.8973x; 1.0076x over previous
//
#include <hip/hip_runtime.h>
#include <cmath>

#define NN 8192
#define DD 512
#define NSRC 8
#define PSW 8                  // ps partials per row = 8 column groups
#define COFF 100.0f            // fixed softmax offset

typedef __bf16 bf16x8 __attribute__((ext_vector_type(8)));
typedef float  f32x4  __attribute__((ext_vector_type(4)));

__device__ __forceinline__ unsigned short f2bf(float f) {
    unsigned u = __float_as_uint(f);
    u += 0x7fffu + ((u >> 16) & 1u);
    return (unsigned short)(u >> 16);
}

// ---------------------------------------------------------------------------
// Kernel A (R10, kept): blocks 0..127 per-source text sums; blocks 128..:
// wave-per-row cast of img+txt AND per-row img.txt dot (ds) for free.
// ---------------------------------------------------------------------------
__global__ __launch_bounds__(256) void k_prep(
    const float* __restrict__ img, const float* __restrict__ txt,
    const int* __restrict__ labels,
    unsigned short* __restrict__ imgB, unsigned short* __restrict__ txtB,
    float* __restrict__ Tsum, int* __restrict__ counts,
    float* __restrict__ dsv)
{
    const int tid = threadIdx.x;
    if (blockIdx.x >= 128) {
        const int wv   = tid >> 6;
        const int lane = tid & 63;
        const int row  = (blockIdx.x - 128) * 4 + wv;
        const size_t base = (size_t)row * DD + lane * 8;
        const float4 i0 = *(const float4*)(img + base);
        const float4 i1 = *(const float4*)(img + base + 4);
        const float4 t0 = *(const float4*)(txt + base);
        const float4 t1 = *(const float4*)(txt + base + 4);
        union { unsigned short s[8]; uint4 v; } oi, ot;
        oi.s[0] = f2bf(i0.x); oi.s[1] = f2bf(i0.y); oi.s[2] = f2bf(i0.z); oi.s[3] = f2bf(i0.w);
        oi.s[4] = f2bf(i1.x); oi.s[5] = f2bf(i1.y); oi.s[6] = f2bf(i1.z); oi.s[7] = f2bf(i1.w);
        ot.s[0] = f2bf(t0.x); ot.s[1] = f2bf(t0.y); ot.s[2] = f2bf(t0.z); ot.s[3] = f2bf(t0.w);
        ot.s[4] = f2bf(t1.x); ot.s[5] = f2bf(t1.y); ot.s[6] = f2bf(t1.z); ot.s[7] = f2bf(t1.w);
        *(uint4*)(imgB + base) = oi.v;
        *(uint4*)(txtB + base) = ot.v;
        float ds = i0.x * t0.x + i0.y * t0.y + i0.z * t0.z + i0.w * t0.w
                 + i1.x * t1.x + i1.y * t1.y + i1.z * t1.z + i1.w * t1.w;
#pragma unroll
        for (int off = 32; off; off >>= 1) ds += __shfl_xor(ds, off);
        if (lane == 0) dsv[row] = ds;
        return;
    }
    __shared__ float Tacc[NSRC * DD];
    __shared__ int cacc[NSRC];
    const int d0 = 2 * tid;
#pragma unroll
    for (int s = 0; s < NSRC; s++) {
        Tacc[s * DD + d0] = 0.f;
        Tacc[s * DD + d0 + 1] = 0.f;
    }
    if (tid < NSRC) cacc[tid] = 0;
    __syncthreads();

    const int row0 = blockIdx.x * 64;
    if (tid < 64) atomicAdd(&cacc[labels[row0 + tid]], 1);

    for (int j = 0; j < 64; j++) {
        const int lab = labels[row0 + j];
        const float2 v = *(const float2*)(txt + (size_t)(row0 + j) * DD + d0);
        Tacc[lab * DD + d0]     += v.x;
        Tacc[lab * DD + d0 + 1] += v.y;
    }
    __syncthreads();
#pragma unroll
    for (int k = 0; k < NSRC * DD / 256; k++) {
        const int e = k * 256 + tid;
        atomicAdd(&Tsum[e], Tacc[e]);
    }
    if (tid < NSRC) atomicAdd(&counts[tid], cacc[tid]);
}

// ---------------------------------------------------------------------------
// Kernel B (R11): R9's 4-phase fragment pattern + register liveness,
// MINIMAL BARRIERS: 2/tile (was 8). Audit: only two barriers are load-bearing
//   bar_M (after JH1): af reads of buf A-q0/q2 done block-wide before JH2's
//          STG2 overwrites them (readers: wr0->q0, wr2->q2 at JH0)
//   bar_S (after JH3 + vmcnt(2)): publishes tile t+1 (all waves' staging
//          landed) AND retires all buf reads (each wave's reads complete
//          before its JH3 MFMA waitcnt) before the next STG6 overwrites.
// JH1/JH3 barriers removed -> waves decouple within each half-tile: one
// wave's JH1 ds_reads drain while another's JH0 MFMAs run (m114 cross-wave
// overlap), per-wave program order unchanged. sched_barrier(0) stays inside
// each phase (no cross-phase hoisting -> liveness stays ~210 regs).
// vmcnt algebra byte-identical to R4/R9: outstanding 2+6+2=10, vmcnt(2)
// retires exactly one whole tile. Spill tripwire: WRITE_SIZE must stay 256B.
// Fallback if pathology/spill: revert this kernel to R9's phase machine.
// ---------------------------------------------------------------------------
__global__ __launch_bounds__(512, 2) void k_lse_mfma256(
    const unsigned short* __restrict__ imgB, const unsigned short* __restrict__ txtB,
    const float* __restrict__ scale_p, float* __restrict__ ps)
{
    __shared__ uint4 lds[8192];            // 128 KiB
    const float scale = scale_p[0];
    const int tid  = threadIdx.x;
    const int lane = tid & 63;
    const int w    = tid >> 6;
    const int wr   = w >> 1;               // 0..3: 64-row quarter
    const int wc   = w & 1;                // 0..1: 128-col half
    const int lq   = lane >> 4;
    const int ln   = lane & 15;
    const int c    = blockIdx.x & 7;       // XCD (round-robin dispatch)
    const int l    = blockIdx.x >> 3;
    const int by   = c * 4 + (l >> 3);     // row panel 0..31
    const int bcg  = l & 7;                // column group 0..7
    const int row0    = by * 256;
    const int colBase = bcg * 1024;

    const int st_r  = tid >> 3;
    const int st_kc = (tid & 7) ^ (st_r & 7);
    const int xsw   = ln & 7;

    // precomputed ds_read base byte-offsets [buf][ks]; ii/jh/jj deltas are
    // compile-time and fold into the ds_read offset immediate.
    int aA[2][2], aB[2][2];
#pragma unroll
    for (int b = 0; b < 2; b++)
#pragma unroll
        for (int ks = 0; ks < 2; ks++) {
            const int perm = ((ks << 2) + lq) ^ xsw;
            aA[b][ks] = b * 65536 + (wr * 64 + ln) * 128 + perm * 16;
            aB[b][ks] = b * 65536 + 32768 + (wc * 128 + ln) * 128 + perm * 16;
        }
    const unsigned short* gA0 = imgB + (size_t)(row0 + st_r) * DD + (st_kc << 3);
    const unsigned short* gB0 = txtB + (size_t)(colBase + st_r) * DD + (st_kc << 3);

#define SA(BUF, Q, T)                                                          \
    { const unsigned short* g = gA0 + ((Q) << 15) + (((T) & 7) << 6);          \
      __builtin_amdgcn_global_load_lds(                                        \
          (const __attribute__((address_space(1))) void*)g,                    \
          (__attribute__((address_space(3))) void*)                            \
              &lds[(BUF) * 4096 + (Q) * 512 + tid], 16, 0, 0); }
#define SB(BUF, Q, T)                                                          \
    { const unsigned short* g = gB0 + ((size_t)(((T) >> 3) & 3) << 17)         \
          + ((Q) << 15) + (((T) & 7) << 6);                                    \
      __builtin_amdgcn_global_load_lds(                                        \
          (const __attribute__((address_space(1))) void*)g,                    \
          (__attribute__((address_space(3))) void*)                            \
              &lds[(BUF) * 4096 + 2048 + (Q) * 512 + tid], 16, 0, 0); }

// Phase JH of the tile in BUF (no barrier inside): reads -> STG ->
// sched_barrier -> setprio(1) MFMA setprio(0). RA=1 only at JH0.
#define PH_(BUF, JH, RA, STG)                                                  \
    do {                                                                       \
        if (RA) {                                                              \
            _Pragma("unroll") for (int ks = 0; ks < 2; ks++)                   \
                _Pragma("unroll") for (int ii = 0; ii < 4; ii++)               \
                    af[ii][ks] = *reinterpret_cast<const bf16x8*>(             \
                        (const char*)lds + aA[BUF][ks] + ii * 2048);           \
        }                                                                      \
        bf16x8 bf[2][2];                                                       \
        _Pragma("unroll") for (int ks = 0; ks < 2; ks++)                       \
            _Pragma("unroll") for (int jj = 0; jj < 2; jj++)                   \
                bf[jj][ks] = *reinterpret_cast<const bf16x8*>(                 \
                    (const char*)lds + aB[BUF][ks] + (JH) * 4096 + jj * 2048); \
        STG;                                                                   \
        __builtin_amdgcn_sched_barrier(0);                                     \
        __builtin_amdgcn_s_setprio(1);                                         \
        _Pragma("unroll") for (int ks = 0; ks < 2; ks++) {                     \
            _Pragma("unroll") for (int ii = 0; ii < 4; ii++) {                 \
                _Pragma("unroll") for (int jj = 0; jj < 2; jj++) {             \
                    acc[ii][(JH) * 2 + jj] =                                   \
                        __builtin_amdgcn_mfma_f32_16x16x32_bf16(               \
                            af[ii][ks], bf[jj][ks], acc[ii][(JH) * 2 + jj],    \
                            0, 0, 0);                                          \
                }                                                              \
            }                                                                  \
        }                                                                      \
        __builtin_amdgcn_s_setprio(0);                                         \
    } while (0)

    // ---- prologue: tile 0 fully + tile 1 Aq0,Aq2 (as R4/R9) ----
#pragma unroll
    for (int q = 0; q < 4; q++) SA(0, q, 0);
#pragma unroll
    for (int q = 0; q < 4; q++) SB(0, q, 0);
    SA(1, 0, 1); SA(1, 2, 1);
    asm volatile("s_waitcnt vmcnt(2)" ::: "memory");   // tile 0 landed
    __builtin_amdgcn_s_barrier();

    f32x4 acc[4][8];
    f32x4 s_run[4];
#pragma unroll
    for (int i = 0; i < 4; i++) {
        s_run[i] = (f32x4){0.f, 0.f, 0.f, 0.f};
#pragma unroll
        for (int j = 0; j < 8; j++) acc[i][j] = (f32x4){0.f, 0.f, 0.f, 0.f};
    }
    bf16x8 af[4][2];

#pragma unroll 1
    for (int v0 = 0; v0 < 32; v0 += 2) {
        // ---- tile t (buf0) ----
        PH_(0, 0, 1,
            SA(1, 1, v0 + 1); SA(1, 3, v0 + 1);
            SB(1, 0, v0 + 1); SB(1, 1, v0 + 1);
            SB(1, 2, v0 + 1); SB(1, 3, v0 + 1));
        PH_(0, 1, 0, (void)0);
        __builtin_amdgcn_s_barrier();      // bar_M: af(buf0) reads retired
        PH_(0, 2, 0, SA(0, 0, v0 + 2); SA(0, 2, v0 + 2));
        PH_(0, 3, 0, (void)0);
        asm volatile("s_waitcnt vmcnt(2)" ::: "memory");
        __builtin_amdgcn_s_barrier();      // bar_S: t+1 landed, buf0 retired
        // ---- tile t+1 (buf1) ----
        PH_(1, 0, 1,
            SA(0, 1, v0 + 2); SA(0, 3, v0 + 2);
            SB(0, 0, v0 + 2); SB(0, 1, v0 + 2);
            SB(0, 2, v0 + 2); SB(0, 3, v0 + 2));
        PH_(1, 1, 0, (void)0);
        __builtin_amdgcn_s_barrier();      // bar_M'
        PH_(1, 2, 0, SA(1, 0, v0 + 3); SA(1, 2, v0 + 3));
        PH_(1, 3, 0, (void)0);
        asm volatile("s_waitcnt vmcnt(2)" ::: "memory");
        __builtin_amdgcn_s_barrier();      // bar_S'
        if ((v0 & 6) == 6) {
            // ct boundary: register-only exp flush (no barrier, no loads)
#pragma unroll
            for (int i = 0; i < 4; i++) {
#pragma unroll
                for (int rg = 0; rg < 4; rg++) {
                    float es = s_run[i][rg];
#pragma unroll
                    for (int j = 0; j < 8; j++)
                        es += __expf(fmaf(acc[i][j][rg], scale, -COFF));
                    s_run[i][rg] = es;
                }
#pragma unroll
                for (int j = 0; j < 8; j++)
                    acc[i][j] = (f32x4){0.f, 0.f, 0.f, 0.f};
            }
        }
    }

    asm volatile("s_waitcnt vmcnt(0)" ::: "memory");
    __syncthreads();

    // ---- epilogue: reduce s_run across ln, fold 2 wc-waves via LDS ----
    float* fred = (float*)lds;             // 256 rows x 2 wc floats
#pragma unroll
    for (int i = 0; i < 4; i++) {
#pragma unroll
        for (int rg = 0; rg < 4; rg++) {
            float es = s_run[i][rg];
#pragma unroll
            for (int off = 8; off; off >>= 1) es += __shfl_xor(es, off);
            if (ln == 0)
                fred[(wr * 64 + i * 16 + lq * 4 + rg) * 2 + wc] = es;
        }
    }
    __syncthreads();
    if (tid < 256) {
        const float tot = fred[tid * 2] + fred[tid * 2 + 1];
        ps[(size_t)(row0 + tid) * PSW + bcg] = tot;
    }
#undef SA
#undef SB
#undef PH_
}

// ---------------------------------------------------------------------------
// Kernel C (R10, kept): dt via bf16 imgB . fp32 Tsum; ds precomputed.
// ---------------------------------------------------------------------------
__global__ __launch_bounds__(256) void k_finalize(
    const unsigned short* __restrict__ imgB,
    const int* __restrict__ labels, const float* __restrict__ scale_p,
    const float* __restrict__ Tsum, const int* __restrict__ counts,
    const float* __restrict__ ps, const float* __restrict__ dsv,
    float* __restrict__ out)
{
    const float scale = scale_p[0];
    const int tid = threadIdx.x;
    const int lane = tid & 63;
    const int wave = tid >> 6;
    const int rowBase = blockIdx.x * 16 + wave * 4;
    float local = 0.f;
#pragma unroll
    for (int it = 0; it < 4; it++) {
        const int i = rowBase + it;
        const int lab = labels[i];
        const float* sp = Tsum + lab * DD + lane * 8;
        union { uint4 v; unsigned short s[8]; } iv;
        iv.v = *(const uint4*)(imgB + (size_t)i * DD + lane * 8);
        const float4 s0 = *(const float4*)(sp);
        const float4 s1 = *(const float4*)(sp + 4);
        float dt = 0.f;
        dt = fmaf(__uint_as_float((unsigned)iv.s[0] << 16), s0.x, dt);
        dt = fmaf(__uint_as_float((unsigned)iv.s[1] << 16), s0.y, dt);
        dt = fmaf(__uint_as_float((unsigned)iv.s[2] << 16), s0.z, dt);
        dt = fmaf(__uint_as_float((unsigned)iv.s[3] << 16), s0.w, dt);
        dt = fmaf(__uint_as_float((unsigned)iv.s[4] << 16), s1.x, dt);
        dt = fmaf(__uint_as_float((unsigned)iv.s[5] << 16), s1.y, dt);
        dt = fmaf(__uint_as_float((unsigned)iv.s[6] << 16), s1.z, dt);
        dt = fmaf(__uint_as_float((unsigned)iv.s[7] << 16), s1.w, dt);
        float es = (lane < PSW) ? ps[(size_t)i * PSW + lane] : 0.f;
#pragma unroll
        for (int off = 32; off; off >>= 1) {
            dt += __shfl_xor(dt, off);
            es += __shfl_xor(es, off);
        }
        if (lane == 0) {
            const float lse = COFF + __logf(es);
            const int cnt = counts[lab] - 1;
            if (cnt > 0) {
                const float row_sum = scale * (dt - dsv[i]) - (float)cnt * lse;
                local += row_sum / (float)cnt;
            }
        }
    }
    __shared__ float red[4];
    if (lane == 0) red[wave] = local;
    __syncthreads();
    if (tid == 0) {
        const float t = red[0] + red[1] + red[2] + red[3];
        atomicAdd(out, -t / (float)NN);
    }
}

// ---------------------------------------------------------------------------
extern "C" void kernel_launch(void* const* d_in, const int* in_sizes, int n_in,
                              void* d_out, int out_size, void* d_ws, size_t ws_size,
                              hipStream_t stream)
{
    const float* img     = (const float*)d_in[0];
    const float* txt     = (const float*)d_in[1];
    const float* scale_p = (const float*)d_in[2];
    const int*   labels  = (const int*)d_in[3];
    float* out = (float*)d_out;

    char* ws = (char*)d_ws;
    float* ps    = (float*)(ws);                                  // 256 KB (8192 x 8)
    float* Tsum  = (float*)(ws + (1 << 18));                      // 16 KB
    int*   counts = (int*)(ws + (1 << 18) + NSRC * DD * 4);
    float* dsv   = (float*)(ws + 0x48000);                        // 32 KB
    unsigned short* imgB = (unsigned short*)(ws + 2 * 1024 * 1024);   // 8 MB
    unsigned short* txtB = (unsigned short*)(ws + 10 * 1024 * 1024);  // 8 MB

    hipMemsetAsync(ws + (1 << 18), 0, NSRC * DD * 4 + 64, stream);  // Tsum+counts
    hipMemsetAsync(d_out, 0, 4, stream);                            // out

    k_prep<<<128 + NN / 4, 256, 0, stream>>>(
        img, txt, labels, imgB, txtB, Tsum, counts, dsv);
    k_lse_mfma256<<<256, 512, 0, stream>>>(imgB, txtB, scale_p, ps);
    k_finalize<<<NN / 16, 256, 0, stream>>>(imgB, labels, scale_p,
                                            Tsum, counts, ps, dsv, out);
}